// Round 13
// baseline (391.338 us; speedup 1.0000x reference)
//
#include <hip/hip_runtime.h>

typedef __attribute__((ext_vector_type(8))) _Float16 half8;
typedef __attribute__((ext_vector_type(4))) _Float16 half4v;
typedef __attribute__((ext_vector_type(2))) _Float16 half2v;
typedef __attribute__((ext_vector_type(4))) float f32x4;

constexpr int NN  = 50000;
constexpr int NE  = 150000;
constexpr int IN  = 16;
constexpr int HID = 32;
constexpr int LAT = 16;
constexpr int EF  = 8;
constexpr int HE  = 128;
constexpr int NTILE = NE / 16;      // 9375 (exact)
constexpr int HSTR  = HE + 2;       // weight-table kk rows (b2 at 128, 0 at 129)

constexpr int SCB = 256;
constexpr int NSB = (NN + SCB - 1) / SCB;   // 196

// A-fragment / h union
union XU {
  half2v h2[4];
  half8  h8;
  _Float16 h[8];
};

// ---------------------------------------------------------------------------
// CSR build (verified rounds 4-12)
// ---------------------------------------------------------------------------
__global__ void count_kernel(const int* __restrict__ dst, int* __restrict__ cnt) {
  int e = blockIdx.x * blockDim.x + threadIdx.x;
  if (e < NE) atomicAdd(&cnt[dst[e]], 1);
}

__launch_bounds__(SCB)
__global__ void scan1(const int* __restrict__ cnt, int* __restrict__ bsum) {
  __shared__ int sdata[SCB];
  const int i = blockIdx.x * SCB + threadIdx.x;
  sdata[threadIdx.x] = (i < NN) ? cnt[i] : 0;
  __syncthreads();
  for (int off = SCB / 2; off > 0; off >>= 1) {
    if (threadIdx.x < off) sdata[threadIdx.x] += sdata[threadIdx.x + off];
    __syncthreads();
  }
  if (threadIdx.x == 0) bsum[blockIdx.x] = sdata[0];
}

__launch_bounds__(SCB)
__global__ void scan2(int* __restrict__ bsum) {
  __shared__ int sdata[SCB];
  const int t = threadIdx.x;
  const int v = (t < NSB) ? bsum[t] : 0;
  sdata[t] = v;
  __syncthreads();
  for (int off = 1; off < SCB; off <<= 1) {
    int u = (t >= off) ? sdata[t - off] : 0;
    __syncthreads();
    sdata[t] += u;
    __syncthreads();
  }
  if (t < NSB) bsum[t] = sdata[t] - v;  // exclusive
}

__launch_bounds__(SCB)
__global__ void scan3(const int* __restrict__ cnt, const int* __restrict__ bsum,
                      int* __restrict__ rowptr, int* __restrict__ wptr) {
  __shared__ int sdata[SCB];
  const int i = blockIdx.x * SCB + threadIdx.x;
  const int t = threadIdx.x;
  const int v = (i < NN) ? cnt[i] : 0;
  sdata[t] = v;
  __syncthreads();
  for (int off = 1; off < SCB; off <<= 1) {
    int u = (t >= off) ? sdata[t - off] : 0;
    __syncthreads();
    sdata[t] += u;
    __syncthreads();
  }
  const int excl = sdata[t] - v + bsum[blockIdx.x];
  if (i < NN) {
    rowptr[i] = excl;
    wptr[i]   = excl;
  }
  if (i == NN - 1) rowptr[NN] = NE;
}

__global__ void fill_kernel(const int* __restrict__ dst, int* __restrict__ wptr,
                            int* __restrict__ epos) {
  int e = blockIdx.x * blockDim.x + threadIdx.x;
  if (e < NE) epos[e] = atomicAdd(&wptr[dst[e]], 1);
}

// ---------------------------------------------------------------------------
// Weight prep (verified round 10): w2 -> fp16 [kk][o][i] (+b2 row), and
// w1 [i][kk] -> w1t [kk][i] fp32 for wave-uniform s_loads in build_h
// ---------------------------------------------------------------------------
__global__ void swizzle_kernel(const float* __restrict__ w2, const float* __restrict__ b2,
                               const float* __restrict__ w1,
                               _Float16* __restrict__ w2h, float* __restrict__ w1t,
                               int DIN_, int DOUT_) {
  int idx = blockIdx.x * blockDim.x + threadIdx.x;
  if (idx < HE * EF) {                 // w1t[kk][i] = w1[i][kk]
    int kk = idx / EF, i = idx % EF;
    w1t[idx] = w1[i * HE + kk];
  }
  int tot = HSTR * DIN_ * DOUT_;
  if (idx >= tot) return;
  int i  = idx % DIN_;
  int o  = (idx / DIN_) % DOUT_;
  int kk = idx / (DIN_ * DOUT_);
  float v = 0.0f;
  if (kk < HE)       v = w2[(size_t)kk * DIN_ * DOUT_ + i * DOUT_ + o];
  else if (kk == HE) v = b2[i * DOUT_ + o];
  w2h[idx] = (_Float16)v;
}

// ---------------------------------------------------------------------------
// MFMA edge kernel, K-SPLIT (round 13): gridDim.y = 2; block (x, yh) handles
// kk in [yh*64, yh*64+64). LDS h table holds only this half (18.4 KB -> 8
// blocks/CU; grid 2344 finally fills the occupancy ceiling). b2 epilogue in
// yh==0 only. Partial msg written to mout = msg + yh*NE*DOUT (no atomics);
// finish kernels sum both partials.
// Block = 128 thr = 2 waves (paired waves share L1 on B-loads — rounds 11/12
// both showed breaking the pairing regresses). Per-K-step code byte-identical
// to verified round 10; DUAL = sequential mu-pass / h-rebuild / lv-pass.
// ---------------------------------------------------------------------------
template <int DIN, int DOUT, bool DUAL>
__launch_bounds__(128)
__global__ void nnconv_mfma(const float* __restrict__ xin,
                            const int*   __restrict__ src,
                            const float* __restrict__ ea,
                            const float* __restrict__ w1tA,  // [HE][EF] fp32
                            const float* __restrict__ b1A,
                            const float* __restrict__ w1tB,  // DUAL only
                            const float* __restrict__ b1B,   // DUAL only
                            const _Float16* __restrict__ w2hA, // [HSTR][DOUT][DIN]
                            const _Float16* __restrict__ w2hB, // DUAL only
                            const int*   __restrict__ epos,
                            _Float16* __restrict__ msgA,       // partials: +yh*NE*DOUT
                            _Float16* __restrict__ msgB)       // DUAL only
{
  constexpr int KKSTEP  = 32 / DIN;             // kk consumed per MFMA step
  constexpr int CHS     = 8 / KKSTEP;           // steps per 8-kk chunk (8 / 4)
  constexpr int BSTRIDE = KKSTEP * DOUT * DIN;  // elements per step
  constexpr int HS      = 72;                   // h LDS row stride (64 kk + pad)
  constexpr int CPB     = 8;                    // chunks per block (64 kk)
  constexpr int TILES   = 4;

  __shared__ _Float16 h_s[128 * HS];     // 18.4 KB

  const int tid  = threadIdx.x;
  const int wave = tid >> 6;
  const int lane = tid & 63;
  const int eb   = blockIdx.x * 128;
  const int yh   = blockIdx.y;           // kk half: [yh*64, yh*64+64)

  // ---- ea straight into registers (thread = edge) ----
  float eav[EF];
  {
    const int e = eb + tid;
    float4 v0 = make_float4(0.f, 0.f, 0.f, 0.f), v1 = v0;
    if (e < NE) {
      const float4* p = (const float4*)(ea + (size_t)e * EF);
      v0 = p[0]; v1 = p[1];
    }
    eav[0] = v0.x; eav[1] = v0.y; eav[2] = v0.z; eav[3] = v0.w;
    eav[4] = v1.x; eav[5] = v1.y; eav[6] = v1.z; eav[7] = v1.w;
  }

  // ---- phase 1: h for own edge, kk in this block's half ----
  auto build_h = [&](const float* __restrict__ w1t, const float* __restrict__ b1) {
#pragma unroll 1
    for (int c = 0; c < CPB; c++) {
      const int kk0 = yh * 64 + c * 8;
      const float4 bq0 = *(const float4*)&b1[kk0];
      const float4 bq1 = *(const float4*)&b1[kk0 + 4];
      const float bk[8] = {bq0.x, bq0.y, bq0.z, bq0.w, bq1.x, bq1.y, bq1.z, bq1.w};
      XU hr;
#pragma unroll
      for (int j = 0; j < 8; j++) {
        const int kk = kk0 + j;
        const float4 wa = *(const float4*)&w1t[kk * EF];
        const float4 wb = *(const float4*)&w1t[kk * EF + 4];
        float hv = bk[j];
        hv = fmaf(eav[0], wa.x, hv); hv = fmaf(eav[1], wa.y, hv);
        hv = fmaf(eav[2], wa.z, hv); hv = fmaf(eav[3], wa.w, hv);
        hv = fmaf(eav[4], wb.x, hv); hv = fmaf(eav[5], wb.y, hv);
        hv = fmaf(eav[6], wb.z, hv); hv = fmaf(eav[7], wb.w, hv);
        hv = fmaxf(hv, 0.0f);
        hr.h[j] = (_Float16)hv;
      }
      *(half8*)&h_s[tid * HS + c * 8] = hr.h8;
    }
  };

  build_h(w1tA, b1A);
  __syncthreads();

  // ---- phase 2 common setup (verified round 10) ----
  const int m = lane & 15, q = lane >> 4;
  const int i0 = (q * 8) % DIN;
  const int kq = (q * 8) / DIN;          // 0 (DIN32) or 0/1 (DIN16)
  const int tg0 = blockIdx.x * 8 + wave * TILES;

  XU xv[TILES];
#pragma unroll
  for (int t = 0; t < TILES; t++) {
    const int tg = tg0 + t;
    if (tg < NTILE) {
      const int s = src[tg * 16 + m];
      const float4* xp = (const float4*)(xin + (size_t)s * DIN + i0);
      const float4 a = xp[0], b = xp[1];
      xv[t].h2[0] = (half2v){(_Float16)a.x, (_Float16)a.y};
      xv[t].h2[1] = (half2v){(_Float16)a.z, (_Float16)a.w};
      xv[t].h2[2] = (half2v){(_Float16)b.x, (_Float16)b.y};
      xv[t].h2[3] = (half2v){(_Float16)b.z, (_Float16)b.w};
    } else {
#pragma unroll
      for (int j = 0; j < 4; j++) xv[t].h2[j] = (half2v){(_Float16)0.f, (_Float16)0.f};
    }
  }

  int hrow[TILES];
#pragma unroll
  for (int t = 0; t < TILES; t++) hrow[t] = wave * 64 + t * 16 + m;

  auto make_af = [&](const XU& xvt, _Float16 hv) -> XU {
    const half2v hb = (half2v){hv, hv};
    XU af;
#pragma unroll
    for (int j = 0; j < 4; j++) af.h2[j] = xvt.h2[j] * hb;   // v_pk_mul_f16
    return af;
  };

  // global step offset of this block's kk half
  const int stepbase = yh * CPB * CHS;

  if constexpr (DUAL) {
    f32x4 acc[TILES][2];
#pragma unroll
    for (int t = 0; t < TILES; t++)
#pragma unroll
      for (int f = 0; f < 2; f++) acc[t][f] = (f32x4){0.f, 0.f, 0.f, 0.f};

    auto run_pass = [&](const _Float16* __restrict__ bp, const int f) {
#pragma unroll 1
      for (int c = 0; c < CPB; c++) {
        XU hc[TILES];
#pragma unroll
        for (int t = 0; t < TILES; t++)
          hc[t].h8 = *(const half8*)&h_s[hrow[t] * HS + c * 8];
#pragma unroll
        for (int s = 0; s < CHS; s++) {
          const half8 bf =
              *(const half8*)(bp + (size_t)(stepbase + c * CHS + s) * BSTRIDE);
#pragma unroll
          for (int t = 0; t < TILES; t++) {
            _Float16 hv;
            if (DIN == 32) hv = hc[t].h[s];
            else {
              const _Float16 h0 = hc[t].h[2 * s], h1 = hc[t].h[2 * s + 1];
              hv = kq ? h1 : h0;
            }
            const XU af = make_af(xv[t], hv);
            acc[t][f] = __builtin_amdgcn_mfma_f32_16x16x32_f16(af.h8, bf,
                                                               acc[t][f], 0, 0, 0);
          }
        }
      }
      // b2 epilogue: kk = 128, h == 1 (y-half 0 only)
      if (yh == 0) {
        const half8 bf = *(const half8*)(bp + (size_t)(128 / KKSTEP) * BSTRIDE);
#pragma unroll
        for (int t = 0; t < TILES; t++) {
          XU af;
          if (DIN == 32) af = xv[t];
          else {
#pragma unroll
            for (int j = 0; j < 4; j++)
              af.h2[j] = kq ? (half2v){(_Float16)0.f, (_Float16)0.f} : xv[t].h2[j];
          }
          acc[t][f] = __builtin_amdgcn_mfma_f32_16x16x32_f16(af.h8, bf,
                                                             acc[t][f], 0, 0, 0);
        }
      }
    };

    const _Float16* bpA = w2hA + (size_t)(kq * DOUT + m) * DIN + i0;
    const _Float16* bpB = w2hB + (size_t)(kq * DOUT + m) * DIN + i0;
    run_pass(bpA, 0);
    __syncthreads();              // all waves done reading h_mu
    build_h(w1tB, b1B);
    __syncthreads();
    run_pass(bpB, 1);

    _Float16* moutA = msgA + (size_t)yh * NE * DOUT;
    _Float16* moutB = msgB + (size_t)yh * NE * DOUT;
#pragma unroll
    for (int t = 0; t < TILES; t++) {
      const int tg = tg0 + t;
      if (tg < NTILE) {
        const int ebase = tg * 16 + q * 4;
        const int4 ep = *(const int4*)(epos + ebase);
        const int pr[4] = {ep.x, ep.y, ep.z, ep.w};
#pragma unroll
        for (int r = 0; r < 4; r++) {
          moutA[(size_t)pr[r] * DOUT + m] = (_Float16)acc[t][0][r];
          moutB[(size_t)pr[r] * DOUT + m] = (_Float16)acc[t][1][r];
        }
      }
    }
  } else {
    f32x4 acc[TILES][2];
#pragma unroll
    for (int t = 0; t < TILES; t++)
#pragma unroll
      for (int f = 0; f < 2; f++) acc[t][f] = (f32x4){0.f, 0.f, 0.f, 0.f};

    const _Float16* bp0 = w2hA + (size_t)(kq * DOUT + 0 + m) * DIN + i0;
    const _Float16* bp1 = w2hA + (size_t)(kq * DOUT + 16 + m) * DIN + i0;
#pragma unroll 1
    for (int c = 0; c < CPB; c++) {
      XU hc[TILES];
#pragma unroll
      for (int t = 0; t < TILES; t++)
        hc[t].h8 = *(const half8*)&h_s[hrow[t] * HS + c * 8];
#pragma unroll
      for (int s = 0; s < CHS; s++) {
        const half8 bf0 =
            *(const half8*)(bp0 + (size_t)(stepbase + c * CHS + s) * BSTRIDE);
        const half8 bf1 =
            *(const half8*)(bp1 + (size_t)(stepbase + c * CHS + s) * BSTRIDE);
#pragma unroll
        for (int t = 0; t < TILES; t++) {
          _Float16 hv;
          if (DIN == 32) hv = hc[t].h[s];
          else {
            const _Float16 h0 = hc[t].h[2 * s], h1 = hc[t].h[2 * s + 1];
            hv = kq ? h1 : h0;
          }
          const XU af = make_af(xv[t], hv);
          acc[t][0] = __builtin_amdgcn_mfma_f32_16x16x32_f16(af.h8, bf0,
                                                             acc[t][0], 0, 0, 0);
          acc[t][1] = __builtin_amdgcn_mfma_f32_16x16x32_f16(af.h8, bf1,
                                                             acc[t][1], 0, 0, 0);
        }
      }
    }
    // b2 epilogue: kk = 128, h == 1 (y-half 0 only)
    if (yh == 0) {
      const half8 bf0 = *(const half8*)(bp0 + (size_t)(128 / KKSTEP) * BSTRIDE);
      const half8 bf1 = *(const half8*)(bp1 + (size_t)(128 / KKSTEP) * BSTRIDE);
#pragma unroll
      for (int t = 0; t < TILES; t++) {
        XU af;
        if (DIN == 32) af = xv[t];
        else {
#pragma unroll
          for (int j = 0; j < 4; j++)
            af.h2[j] = kq ? (half2v){(_Float16)0.f, (_Float16)0.f} : xv[t].h2[j];
        }
        acc[t][0] = __builtin_amdgcn_mfma_f32_16x16x32_f16(af.h8, bf0,
                                                           acc[t][0], 0, 0, 0);
        acc[t][1] = __builtin_amdgcn_mfma_f32_16x16x32_f16(af.h8, bf1,
                                                           acc[t][1], 0, 0, 0);
      }
    }

    _Float16* mout = msgA + (size_t)yh * NE * DOUT;
#pragma unroll
    for (int t = 0; t < TILES; t++) {
      const int tg = tg0 + t;
      if (tg < NTILE) {
        const int ebase = tg * 16 + q * 4;
        const int4 ep = *(const int4*)(epos + ebase);
        const int pr[4] = {ep.x, ep.y, ep.z, ep.w};
#pragma unroll
        for (int f = 0; f < 2; f++)
#pragma unroll
          for (int r = 0; r < 4; r++)
            mout[(size_t)pr[r] * DOUT + f * 16 + m] = (_Float16)acc[t][f][r];
      }
    }
  }
}

// ---------------------------------------------------------------------------
// Finish (single): out = (CSR-sum of both fp16 msg partials) /deg? + x@root
// + bias, relu?
// ---------------------------------------------------------------------------
template <int DIN, int DOUT, bool MEAN, bool RELU>
__launch_bounds__(256)
__global__ void finish_kernel(const _Float16* __restrict__ msg,
                              const int* __restrict__ rowptr,
                              const float* __restrict__ xin,
                              const float* __restrict__ root,
                              const float* __restrict__ bias,
                              float* __restrict__ out) {
  constexpr int TPN = DOUT / 4;
  const int gid = blockIdx.x * 256 + threadIdx.x;
  const int n = gid / TPN, sub = gid % TPN;
  if (n >= NN) return;
  const int o0 = sub * 4;
  const _Float16* msg1 = msg + (size_t)NE * DOUT;   // second K-half partial

  const int r0 = rowptr[n], r1 = rowptr[n + 1];
  float ax = 0.f, ay = 0.f, az = 0.f, aw = 0.f;
  for (int idx = r0; idx < r1; idx++) {
    const half4v m0 = *(const half4v*)(msg  + (size_t)idx * DOUT + o0);
    const half4v m1 = *(const half4v*)(msg1 + (size_t)idx * DOUT + o0);
    ax += (float)m0.x + (float)m1.x; ay += (float)m0.y + (float)m1.y;
    az += (float)m0.z + (float)m1.z; aw += (float)m0.w + (float)m1.w;
  }
  const float inv = MEAN ? 1.0f / fmaxf((float)(r1 - r0), 1.0f) : 1.0f;
  float vx = ax * inv + bias[o0 + 0];
  float vy = ay * inv + bias[o0 + 1];
  float vz = az * inv + bias[o0 + 2];
  float vw = aw * inv + bias[o0 + 3];
#pragma unroll
  for (int i = 0; i < DIN; i++) {
    const float xi = xin[(size_t)n * DIN + i];
    const float4 rv = *(const float4*)(root + (size_t)i * DOUT + o0);
    vx = fmaf(xi, rv.x, vx); vy = fmaf(xi, rv.y, vy);
    vz = fmaf(xi, rv.z, vz); vw = fmaf(xi, rv.w, vw);
  }
  if (RELU) {
    vx = fmaxf(vx, 0.f); vy = fmaxf(vy, 0.f);
    vz = fmaxf(vz, 0.f); vw = fmaxf(vw, 0.f);
  }
  *(float4*)(out + (size_t)n * DOUT + o0) = make_float4(vx, vy, vz, vw);
}

// Fused finish for mu+lv (DOUT=LAT=16, no mean, no relu), two partials each
template <int DIN>
__launch_bounds__(256)
__global__ void finish_dual(const _Float16* __restrict__ msgA,
                            const _Float16* __restrict__ msgB,
                            const int* __restrict__ rowptr,
                            const float* __restrict__ xin,
                            const float* __restrict__ rootA,
                            const float* __restrict__ biasA,
                            const float* __restrict__ rootB,
                            const float* __restrict__ biasB,
                            float* __restrict__ outA,
                            float* __restrict__ outB) {
  constexpr int TPN = LAT / 4;
  const int gid = blockIdx.x * 256 + threadIdx.x;
  const int n = gid / TPN, sub = gid % TPN;
  if (n >= NN) return;
  const int o0 = sub * 4;
  const _Float16* msgA1 = msgA + (size_t)NE * LAT;
  const _Float16* msgB1 = msgB + (size_t)NE * LAT;

  const int r0 = rowptr[n], r1 = rowptr[n + 1];
  float a0 = 0.f, a1 = 0.f, a2 = 0.f, a3 = 0.f;
  float b0 = 0.f, b1 = 0.f, b2 = 0.f, b3 = 0.f;
  for (int idx = r0; idx < r1; idx++) {
    const half4v ma0 = *(const half4v*)(msgA  + (size_t)idx * LAT + o0);
    const half4v ma1 = *(const half4v*)(msgA1 + (size_t)idx * LAT + o0);
    const half4v mb0 = *(const half4v*)(msgB  + (size_t)idx * LAT + o0);
    const half4v mb1 = *(const half4v*)(msgB1 + (size_t)idx * LAT + o0);
    a0 += (float)ma0.x + (float)ma1.x; a1 += (float)ma0.y + (float)ma1.y;
    a2 += (float)ma0.z + (float)ma1.z; a3 += (float)ma0.w + (float)ma1.w;
    b0 += (float)mb0.x + (float)mb1.x; b1 += (float)mb0.y + (float)mb1.y;
    b2 += (float)mb0.z + (float)mb1.z; b3 += (float)mb0.w + (float)mb1.w;
  }
  float va0 = a0 + biasA[o0 + 0], va1 = a1 + biasA[o0 + 1];
  float va2 = a2 + biasA[o0 + 2], va3 = a3 + biasA[o0 + 3];
  float vb0 = b0 + biasB[o0 + 0], vb1 = b1 + biasB[o0 + 1];
  float vb2 = b2 + biasB[o0 + 2], vb3 = b3 + biasB[o0 + 3];
#pragma unroll
  for (int i = 0; i < DIN; i++) {
    const float xi = xin[(size_t)n * DIN + i];
    const float4 ra = *(const float4*)(rootA + (size_t)i * LAT + o0);
    const float4 rb = *(const float4*)(rootB + (size_t)i * LAT + o0);
    va0 = fmaf(xi, ra.x, va0); va1 = fmaf(xi, ra.y, va1);
    va2 = fmaf(xi, ra.z, va2); va3 = fmaf(xi, ra.w, va3);
    vb0 = fmaf(xi, rb.x, vb0); vb1 = fmaf(xi, rb.y, vb1);
    vb2 = fmaf(xi, rb.z, vb2); vb3 = fmaf(xi, rb.w, vb3);
  }
  *(float4*)(outA + (size_t)n * LAT + o0) = make_float4(va0, va1, va2, va3);
  *(float4*)(outB + (size_t)n * LAT + o0) = make_float4(vb0, vb1, vb2, vb3);
}

// ---------------------------------------------------------------------------
extern "C" void kernel_launch(void* const* d_in, const int* in_sizes, int n_in,
                              void* d_out, int out_size, void* d_ws, size_t ws_size,
                              hipStream_t stream) {
  const float* x  = (const float*)d_in[0];
  const int*   ei = (const int*)d_in[1];
  const float* ea = (const float*)d_in[2];
  const int* src = ei;
  const int* dst = ei + NE;

  auto P = [&](int c, int j) -> const float* {
    return (const float*)d_in[3 + c * 6 + j];
  };

  // workspace layout (msg region = NE*64 halves: two K-half partials)
  float* h1  = (float*)d_ws;                          // NN*HID f32
  float* h2  = h1 + (size_t)NN * HID;                 // NN*HID f32
  _Float16* msg = (_Float16*)(h2 + (size_t)NN * HID); // NE*64 fp16
  int* cnt    = (int*)(msg + (size_t)NE * 64);        // NN
  int* rowptr = cnt + NN;                             // NN+1 (pad 50004)
  int* wptr   = rowptr + 50004;                       // NN+1 (pad)
  int* epos   = wptr + 50004;                         // NE
  int* bsum   = epos + NE;                            // NSB (pad 256)
  _Float16* w2h_c1 = (_Float16*)(bsum + 256);           // HSTR*32*16
  _Float16* w2h_c2 = w2h_c1 + (size_t)HSTR * 32 * 16;   // HSTR*32*32
  _Float16* w2h_mu = w2h_c2 + (size_t)HSTR * 32 * 32;   // HSTR*16*32
  _Float16* w2h_lv = w2h_mu + (size_t)HSTR * 16 * 32;
  float* w1t_c1 = (float*)(w2h_lv + (size_t)HSTR * 16 * 32);  // HE*EF each
  float* w1t_c2 = w1t_c1 + HE * EF;
  float* w1t_mu = w1t_c2 + HE * EF;
  float* w1t_lv = w1t_mu + HE * EF;

  // non-dual: partials at msg + {0, NE*32}
  // dual: msgA partials at msg + {0, NE*16}; msgB at msg+NE*32 + {0, NE*16}
  _Float16* msgA = msg;
  _Float16* msgB = msg + (size_t)NE * 32;

  float* out_mu = (float*)d_out;
  float* out_lv = out_mu + (size_t)NN * LAT;

  // ---- CSR build ----
  hipMemsetAsync(cnt, 0, (size_t)NN * sizeof(int), stream);
  count_kernel<<<dim3((NE + 255) / 256), dim3(256), 0, stream>>>(dst, cnt);
  scan1<<<dim3(NSB), dim3(SCB), 0, stream>>>(cnt, bsum);
  scan2<<<dim3(1), dim3(SCB), 0, stream>>>(bsum);
  scan3<<<dim3(NSB), dim3(SCB), 0, stream>>>(cnt, bsum, rowptr, wptr);
  fill_kernel<<<dim3((NE + 255) / 256), dim3(256), 0, stream>>>(dst, wptr, epos);

  // ---- weight prep (w2 swizzle + w1 transpose) ----
  {
    int t1 = HSTR * 16 * 32, t2 = HSTR * 32 * 32, t3 = HSTR * 32 * 16;
    swizzle_kernel<<<dim3((t1 + 255) / 256), dim3(256), 0, stream>>>(
        P(0, 2), P(0, 3), P(0, 0), w2h_c1, w1t_c1, IN, HID);
    swizzle_kernel<<<dim3((t2 + 255) / 256), dim3(256), 0, stream>>>(
        P(1, 2), P(1, 3), P(1, 0), w2h_c2, w1t_c2, HID, HID);
    swizzle_kernel<<<dim3((t3 + 255) / 256), dim3(256), 0, stream>>>(
        P(2, 2), P(2, 3), P(2, 0), w2h_mu, w1t_mu, HID, LAT);
    swizzle_kernel<<<dim3((t3 + 255) / 256), dim3(256), 0, stream>>>(
        P(3, 2), P(3, 3), P(3, 0), w2h_lv, w1t_lv, HID, LAT);
  }

  const dim3 egrid((NTILE + 7) / 8, 2), eblk(128);  // 128 edges, 2 K-halves

  // conv1: 16 -> 32, mean, relu
  nnconv_mfma<IN, HID, false><<<egrid, eblk, 0, stream>>>(
      x, src, ea, w1t_c1, P(0, 1), nullptr, nullptr, w2h_c1, nullptr,
      epos, msgA, nullptr);
  finish_kernel<IN, HID, true, true>
      <<<dim3((NN * (HID / 4) + 255) / 256), dim3(256), 0, stream>>>(
          msgA, rowptr, x, P(0, 4), P(0, 5), h1);

  // conv2: 32 -> 32, mean, relu
  nnconv_mfma<HID, HID, false><<<egrid, eblk, 0, stream>>>(
      h1, src, ea, w1t_c2, P(1, 1), nullptr, nullptr, w2h_c2, nullptr,
      epos, msgA, nullptr);
  finish_kernel<HID, HID, true, true>
      <<<dim3((NN * (HID / 4) + 255) / 256), dim3(256), 0, stream>>>(
          msgA, rowptr, h1, P(1, 4), P(1, 5), h2);

  // cmu + clv fused (sequential passes per block; K-split across blocks)
  nnconv_mfma<HID, LAT, true><<<egrid, eblk, 0, stream>>>(
      h2, src, ea, w1t_mu, P(2, 1), w1t_lv, P(3, 1), w2h_mu, w2h_lv,
      epos, msgA, msgB);
  finish_dual<HID>
      <<<dim3((NN * (LAT / 4) + 255) / 256), dim3(256), 0, stream>>>(
          msgA, msgB, rowptr, h2, P(2, 4), P(2, 5), P(3, 4), P(3, 5),
          out_mu, out_lv);
}

// Round 15
// 343.603 us; speedup vs baseline: 1.1389x; 1.1389x over previous
//
#include <hip/hip_runtime.h>

typedef __attribute__((ext_vector_type(8))) _Float16 half8;
typedef __attribute__((ext_vector_type(4))) _Float16 half4v;
typedef __attribute__((ext_vector_type(2))) _Float16 half2v;
typedef __attribute__((ext_vector_type(4))) float f32x4;

constexpr int NN  = 50000;
constexpr int NE  = 150000;
constexpr int IN  = 16;
constexpr int HID = 32;
constexpr int LAT = 16;
constexpr int EF  = 8;
constexpr int HE  = 128;
constexpr int NTILE = NE / 16;      // 9375 (exact)
constexpr int HSTR  = HE + 2;       // weight-table kk rows (b2 at 128, 0 at 129)

constexpr int SCB = 256;
constexpr int NSB = (NN + SCB - 1) / SCB;   // 196

// A-fragment / h union
union XU {
  half2v h2[4];
  half8  h8;
  _Float16 h[8];
};

// ---------------------------------------------------------------------------
// CSR build (verified rounds 4-13)
// ---------------------------------------------------------------------------
__global__ void count_kernel(const int* __restrict__ dst, int* __restrict__ cnt) {
  int e = blockIdx.x * blockDim.x + threadIdx.x;
  if (e < NE) atomicAdd(&cnt[dst[e]], 1);
}

__launch_bounds__(SCB)
__global__ void scan1(const int* __restrict__ cnt, int* __restrict__ bsum) {
  __shared__ int sdata[SCB];
  const int i = blockIdx.x * SCB + threadIdx.x;
  sdata[threadIdx.x] = (i < NN) ? cnt[i] : 0;
  __syncthreads();
  for (int off = SCB / 2; off > 0; off >>= 1) {
    if (threadIdx.x < off) sdata[threadIdx.x] += sdata[threadIdx.x + off];
    __syncthreads();
  }
  if (threadIdx.x == 0) bsum[blockIdx.x] = sdata[0];
}

__launch_bounds__(SCB)
__global__ void scan2(int* __restrict__ bsum) {
  __shared__ int sdata[SCB];
  const int t = threadIdx.x;
  const int v = (t < NSB) ? bsum[t] : 0;
  sdata[t] = v;
  __syncthreads();
  for (int off = 1; off < SCB; off <<= 1) {
    int u = (t >= off) ? sdata[t - off] : 0;
    __syncthreads();
    sdata[t] += u;
    __syncthreads();
  }
  if (t < NSB) bsum[t] = sdata[t] - v;  // exclusive
}

__launch_bounds__(SCB)
__global__ void scan3(const int* __restrict__ cnt, const int* __restrict__ bsum,
                      int* __restrict__ rowptr, int* __restrict__ wptr) {
  __shared__ int sdata[SCB];
  const int i = blockIdx.x * SCB + threadIdx.x;
  const int t = threadIdx.x;
  const int v = (i < NN) ? cnt[i] : 0;
  sdata[t] = v;
  __syncthreads();
  for (int off = 1; off < SCB; off <<= 1) {
    int u = (t >= off) ? sdata[t - off] : 0;
    __syncthreads();
    sdata[t] += u;
    __syncthreads();
  }
  const int excl = sdata[t] - v + bsum[blockIdx.x];
  if (i < NN) {
    rowptr[i] = excl;
    wptr[i]   = excl;
  }
  if (i == NN - 1) rowptr[NN] = NE;
}

__global__ void fill_kernel(const int* __restrict__ dst, int* __restrict__ wptr,
                            int* __restrict__ epos) {
  int e = blockIdx.x * blockDim.x + threadIdx.x;
  if (e < NE) epos[e] = atomicAdd(&wptr[dst[e]], 1);
}

// ---------------------------------------------------------------------------
// Weight prep (verified round 10): w2 -> fp16 [kk][o][i] (+b2 row), and
// w1 [i][kk] -> w1t [kk][i] fp32 for wave-uniform s_loads in build_h
// ---------------------------------------------------------------------------
__global__ void swizzle_kernel(const float* __restrict__ w2, const float* __restrict__ b2,
                               const float* __restrict__ w1,
                               _Float16* __restrict__ w2h, float* __restrict__ w1t,
                               int DIN_, int DOUT_) {
  int idx = blockIdx.x * blockDim.x + threadIdx.x;
  if (idx < HE * EF) {                 // w1t[kk][i] = w1[i][kk]
    int kk = idx / EF, i = idx % EF;
    w1t[idx] = w1[i * HE + kk];
  }
  int tot = HSTR * DIN_ * DOUT_;
  if (idx >= tot) return;
  int i  = idx % DIN_;
  int o  = (idx / DIN_) % DOUT_;
  int kk = idx / (DIN_ * DOUT_);
  float v = 0.0f;
  if (kk < HE)       v = w2[(size_t)kk * DIN_ * DOUT_ + i * DOUT_ + o];
  else if (kk == HE) v = b2[i * DOUT_ + o];
  w2h[idx] = (_Float16)v;
}

// ---------------------------------------------------------------------------
// MFMA edge kernel (round 14/15): r10 structure + JIT per-chunk h build.
// Block = 128 thr = 2 waves; 128 edges; 4 A-tiles/wave. Per chunk c
// (8 kk): each thread builds h[kk 8c..8c+8) for its edge into a tiny
// double-buffered LDS slab (4-8 KB total vs 34.8 KB full table), one
// barrier, then the r10 chunk body consumes it. LDS no longer caps
// occupancy. Both waves stay barrier-locked on the same B-slab (L1
// pairing kept — r11/r12 showed breaking it regresses). DUAL builds
// mu+lv chunk tables per iteration and fuses both MFMA streams.
// ---------------------------------------------------------------------------
template <int DIN, int DOUT, bool DUAL>
__launch_bounds__(128)
__global__ void nnconv_mfma(const float* __restrict__ xin,
                            const int*   __restrict__ src,
                            const float* __restrict__ ea,
                            const float* __restrict__ w1tA,  // [HE][EF] fp32
                            const float* __restrict__ b1A,
                            const float* __restrict__ w1tB,  // DUAL only
                            const float* __restrict__ b1B,   // DUAL only
                            const _Float16* __restrict__ w2hA, // [HSTR][DOUT][DIN]
                            const _Float16* __restrict__ w2hB, // DUAL only
                            const int*   __restrict__ epos,
                            _Float16* __restrict__ msgA,       // CSR-ordered fp16
                            _Float16* __restrict__ msgB)       // DUAL only
{
  constexpr int KKSTEP  = 32 / DIN;             // kk consumed per MFMA step
  constexpr int CHS     = 8 / KKSTEP;           // steps per 8-kk chunk (8 / 4)
  constexpr int BSTRIDE = KKSTEP * DOUT * DIN;  // elements per step
  constexpr int TILES   = 4;
  constexpr int NTAB    = DUAL ? 2 : 1;

  // [dbuf][table][row 0..127][8 kk] fp16: 4 KB (non-dual) / 8 KB (dual)
  __shared__ _Float16 h_s[2 * NTAB * 128 * 8];

  const int tid  = threadIdx.x;
  const int wave = tid >> 6;
  const int lane = tid & 63;
  const int eb   = blockIdx.x * 128;

  // ---- ea straight into registers (thread = edge) ----
  float eav[EF];
  {
    const int e = eb + tid;
    float4 v0 = make_float4(0.f, 0.f, 0.f, 0.f), v1 = v0;
    if (e < NE) {
      const float4* p = (const float4*)(ea + (size_t)e * EF);
      v0 = p[0]; v1 = p[1];
    }
    eav[0] = v0.x; eav[1] = v0.y; eav[2] = v0.z; eav[3] = v0.w;
    eav[4] = v1.x; eav[5] = v1.y; eav[6] = v1.z; eav[7] = v1.w;
  }

  // JIT h-chunk builder: 8 kk of this thread's edge -> dst[tid*8 .. +8)
  auto build_chunk = [&](const float* __restrict__ w1t,
                         const float* __restrict__ b1,
                         int c, _Float16* __restrict__ dst) {
    const int kk0 = c * 8;
    const float4 bq0 = *(const float4*)&b1[kk0];
    const float4 bq1 = *(const float4*)&b1[kk0 + 4];
    const float bk[8] = {bq0.x, bq0.y, bq0.z, bq0.w, bq1.x, bq1.y, bq1.z, bq1.w};
    XU hr;
#pragma unroll
    for (int j = 0; j < 8; j++) {
      const int kk = kk0 + j;
      const float4 wa = *(const float4*)&w1t[kk * EF];
      const float4 wb = *(const float4*)&w1t[kk * EF + 4];
      float hv = bk[j];
      hv = fmaf(eav[0], wa.x, hv); hv = fmaf(eav[1], wa.y, hv);
      hv = fmaf(eav[2], wa.z, hv); hv = fmaf(eav[3], wa.w, hv);
      hv = fmaf(eav[4], wb.x, hv); hv = fmaf(eav[5], wb.y, hv);
      hv = fmaf(eav[6], wb.z, hv); hv = fmaf(eav[7], wb.w, hv);
      hv = fmaxf(hv, 0.0f);
      hr.h[j] = (_Float16)hv;
    }
    *(half8*)&dst[tid * 8] = hr.h8;
  };

  // ---- phase 2 common setup (verified round 10) ----
  const int m = lane & 15, q = lane >> 4;
  const int i0 = (q * 8) % DIN;
  const int kq = (q * 8) / DIN;          // 0 (DIN32) or 0/1 (DIN16)
  const int tg0 = blockIdx.x * 8 + wave * TILES;

  XU xv[TILES];
#pragma unroll
  for (int t = 0; t < TILES; t++) {
    const int tg = tg0 + t;
    if (tg < NTILE) {
      const int s = src[tg * 16 + m];
      const float4* xp = (const float4*)(xin + (size_t)s * DIN + i0);
      const float4 a = xp[0], b = xp[1];
      xv[t].h2[0] = (half2v){(_Float16)a.x, (_Float16)a.y};
      xv[t].h2[1] = (half2v){(_Float16)a.z, (_Float16)a.w};
      xv[t].h2[2] = (half2v){(_Float16)b.x, (_Float16)b.y};
      xv[t].h2[3] = (half2v){(_Float16)b.z, (_Float16)b.w};
    } else {
#pragma unroll
      for (int j = 0; j < 4; j++) xv[t].h2[j] = (half2v){(_Float16)0.f, (_Float16)0.f};
    }
  }

  f32x4 acc[TILES][2];
#pragma unroll
  for (int t = 0; t < TILES; t++)
#pragma unroll
    for (int f = 0; f < 2; f++) acc[t][f] = (f32x4){0.f, 0.f, 0.f, 0.f};

  int hrow[TILES];
#pragma unroll
  for (int t = 0; t < TILES; t++) hrow[t] = wave * 64 + t * 16 + m;

  auto make_af = [&](const XU& xvt, _Float16 hv) -> XU {
    const half2v hb = (half2v){hv, hv};
    XU af;
#pragma unroll
    for (int j = 0; j < 4; j++) af.h2[j] = xvt.h2[j] * hb;   // v_pk_mul_f16
    return af;
  };

  // B fragment base pointers
  const _Float16* bp0;
  const _Float16* bp1;
  if (DUAL) {
    bp0 = w2hA + (size_t)(kq * DOUT + m) * DIN + i0;
    bp1 = w2hB + (size_t)(kq * DOUT + m) * DIN + i0;
  } else {
    bp0 = w2hA + (size_t)(kq * DOUT + 0 + m) * DIN + i0;
    bp1 = w2hA + (size_t)(kq * DOUT + 16 + m) * DIN + i0;
  }

  // ---- fused K-loop: JIT h build -> barrier -> consume (r10 chunk body) ----
#pragma unroll 1
  for (int c = 0; c < 16; c++) {
    _Float16* buf = &h_s[(size_t)(c & 1) * NTAB * 128 * 8];
    build_chunk(w1tA, b1A, c, buf);
    if (DUAL) build_chunk(w1tB, b1B, c, buf + 128 * 8);
    __syncthreads();   // dbuf makes one barrier/chunk sufficient (WAR-safe)

    XU hc0[TILES], hc1[TILES];
#pragma unroll
    for (int t = 0; t < TILES; t++)
      hc0[t].h8 = *(const half8*)&buf[hrow[t] * 8];
    if (DUAL) {
#pragma unroll
      for (int t = 0; t < TILES; t++)
        hc1[t].h8 = *(const half8*)&buf[128 * 8 + hrow[t] * 8];
    }

#pragma unroll
    for (int s = 0; s < CHS; s++) {
      const half8 bf0 = *(const half8*)(bp0 + (size_t)(c * CHS + s) * BSTRIDE);
      const half8 bf1 = *(const half8*)(bp1 + (size_t)(c * CHS + s) * BSTRIDE);
#pragma unroll
      for (int t = 0; t < TILES; t++) {
        _Float16 hv0;
        if (DIN == 32) hv0 = hc0[t].h[s];
        else {
          const _Float16 h0 = hc0[t].h[2 * s], h1 = hc0[t].h[2 * s + 1];
          hv0 = kq ? h1 : h0;
        }
        const XU af0 = make_af(xv[t], hv0);
        acc[t][0] = __builtin_amdgcn_mfma_f32_16x16x32_f16(af0.h8, bf0,
                                                           acc[t][0], 0, 0, 0);
        if (DUAL) {
          _Float16 hv1;
          if (DIN == 32) hv1 = hc1[t].h[s];
          else {
            const _Float16 h0 = hc1[t].h[2 * s], h1 = hc1[t].h[2 * s + 1];
            hv1 = kq ? h1 : h0;
          }
          const XU af1 = make_af(xv[t], hv1);
          acc[t][1] = __builtin_amdgcn_mfma_f32_16x16x32_f16(af1.h8, bf1,
                                                             acc[t][1], 0, 0, 0);
        } else {
          acc[t][1] = __builtin_amdgcn_mfma_f32_16x16x32_f16(af0.h8, bf1,
                                                             acc[t][1], 0, 0, 0);
        }
      }
    }
  }

  // ---- b2 epilogue: kk = 128, h == 1 (r10, both f-columns) ----
  {
    const half8 bf0 = *(const half8*)(bp0 + (size_t)(128 / KKSTEP) * BSTRIDE);
    const half8 bf1 = *(const half8*)(bp1 + (size_t)(128 / KKSTEP) * BSTRIDE);
#pragma unroll
    for (int t = 0; t < TILES; t++) {
      XU af;
      if (DIN == 32) af = xv[t];
      else {
#pragma unroll
        for (int j = 0; j < 4; j++)
          af.h2[j] = kq ? (half2v){(_Float16)0.f, (_Float16)0.f} : xv[t].h2[j];
      }
      acc[t][0] = __builtin_amdgcn_mfma_f32_16x16x32_f16(af.h8, bf0,
                                                         acc[t][0], 0, 0, 0);
      acc[t][1] = __builtin_amdgcn_mfma_f32_16x16x32_f16(af.h8, bf1,
                                                         acc[t][1], 0, 0, 0);
    }
  }

  // ---- store msg (fp16) in CSR order: D row = q*4+r (edge), col = m ----
#pragma unroll
  for (int t = 0; t < TILES; t++) {
    const int tg = tg0 + t;
    if (tg < NTILE) {
      const int ebase = tg * 16 + q * 4;
      const int4 ep = *(const int4*)(epos + ebase);
      const int pr[4] = {ep.x, ep.y, ep.z, ep.w};
      if (DUAL) {
#pragma unroll
        for (int r = 0; r < 4; r++) {
          msgA[(size_t)pr[r] * DOUT + m] = (_Float16)acc[t][0][r];
          msgB[(size_t)pr[r] * DOUT + m] = (_Float16)acc[t][1][r];
        }
      } else {
#pragma unroll
        for (int f = 0; f < 2; f++)
#pragma unroll
          for (int r = 0; r < 4; r++)
            msgA[(size_t)pr[r] * DOUT + f * 16 + m] = (_Float16)acc[t][f][r];
      }
    }
  }
}

// ---------------------------------------------------------------------------
// Finish (single): out = (CSR-sum of fp16 msg) /deg? + x@root + bias, relu?
// ---------------------------------------------------------------------------
template <int DIN, int DOUT, bool MEAN, bool RELU>
__launch_bounds__(256)
__global__ void finish_kernel(const _Float16* __restrict__ msg,
                              const int* __restrict__ rowptr,
                              const float* __restrict__ xin,
                              const float* __restrict__ root,
                              const float* __restrict__ bias,
                              float* __restrict__ out) {
  constexpr int TPN = DOUT / 4;
  const int gid = blockIdx.x * 256 + threadIdx.x;
  const int n = gid / TPN, sub = gid % TPN;
  if (n >= NN) return;
  const int o0 = sub * 4;

  const int r0 = rowptr[n], r1 = rowptr[n + 1];
  float ax = 0.f, ay = 0.f, az = 0.f, aw = 0.f;
  for (int idx = r0; idx < r1; idx++) {
    const half4v mv = *(const half4v*)(msg + (size_t)idx * DOUT + o0);
    ax += (float)mv.x; ay += (float)mv.y; az += (float)mv.z; aw += (float)mv.w;
  }
  const float inv = MEAN ? 1.0f / fmaxf((float)(r1 - r0), 1.0f) : 1.0f;
  float vx = ax * inv + bias[o0 + 0];
  float vy = ay * inv + bias[o0 + 1];
  float vz = az * inv + bias[o0 + 2];
  float vw = aw * inv + bias[o0 + 3];
#pragma unroll
  for (int i = 0; i < DIN; i++) {
    const float xi = xin[(size_t)n * DIN + i];
    const float4 rv = *(const float4*)(root + (size_t)i * DOUT + o0);
    vx = fmaf(xi, rv.x, vx); vy = fmaf(xi, rv.y, vy);
    vz = fmaf(xi, rv.z, vz); vw = fmaf(xi, rv.w, vw);
  }
  if (RELU) {
    vx = fmaxf(vx, 0.f); vy = fmaxf(vy, 0.f);
    vz = fmaxf(vz, 0.f); vw = fmaxf(vw, 0.f);
  }
  *(float4*)(out + (size_t)n * DOUT + o0) = make_float4(vx, vy, vz, vw);
}

// Fused finish for mu+lv (DOUT=LAT=16, no mean, no relu)
template <int DIN>
__launch_bounds__(256)
__global__ void finish_dual(const _Float16* __restrict__ msgA,
                            const _Float16* __restrict__ msgB,
                            const int* __restrict__ rowptr,
                            const float* __restrict__ xin,
                            const float* __restrict__ rootA,
                            const float* __restrict__ biasA,
                            const float* __restrict__ rootB,
                            const float* __restrict__ biasB,
                            float* __restrict__ outA,
                            float* __restrict__ outB) {
  constexpr int TPN = LAT / 4;
  const int gid = blockIdx.x * 256 + threadIdx.x;
  const int n = gid / TPN, sub = gid % TPN;
  if (n >= NN) return;
  const int o0 = sub * 4;

  const int r0 = rowptr[n], r1 = rowptr[n + 1];
  float a0 = 0.f, a1 = 0.f, a2 = 0.f, a3 = 0.f;
  float b0 = 0.f, b1 = 0.f, b2 = 0.f, b3 = 0.f;
  for (int idx = r0; idx < r1; idx++) {
    const half4v ma = *(const half4v*)(msgA + (size_t)idx * LAT + o0);
    const half4v mb = *(const half4v*)(msgB + (size_t)idx * LAT + o0);
    a0 += (float)ma.x; a1 += (float)ma.y; a2 += (float)ma.z; a3 += (float)ma.w;
    b0 += (float)mb.x; b1 += (float)mb.y; b2 += (float)mb.z; b3 += (float)mb.w;
  }
  float va0 = a0 + biasA[o0 + 0], va1 = a1 + biasA[o0 + 1];
  float va2 = a2 + biasA[o0 + 2], va3 = a3 + biasA[o0 + 3];
  float vb0 = b0 + biasB[o0 + 0], vb1 = b1 + biasB[o0 + 1];
  float vb2 = b2 + biasB[o0 + 2], vb3 = b3 + biasB[o0 + 3];
#pragma unroll
  for (int i = 0; i < DIN; i++) {
    const float xi = xin[(size_t)n * DIN + i];
    const float4 ra = *(const float4*)(rootA + (size_t)i * LAT + o0);
    const float4 rb = *(const float4*)(rootB + (size_t)i * LAT + o0);
    va0 = fmaf(xi, ra.x, va0); va1 = fmaf(xi, ra.y, va1);
    va2 = fmaf(xi, ra.z, va2); va3 = fmaf(xi, ra.w, va3);
    vb0 = fmaf(xi, rb.x, vb0); vb1 = fmaf(xi, rb.y, vb1);
    vb2 = fmaf(xi, rb.z, vb2); vb3 = fmaf(xi, rb.w, vb3);
  }
  *(float4*)(outA + (size_t)n * LAT + o0) = make_float4(va0, va1, va2, va3);
  *(float4*)(outB + (size_t)n * LAT + o0) = make_float4(vb0, vb1, vb2, vb3);
}

// ---------------------------------------------------------------------------
extern "C" void kernel_launch(void* const* d_in, const int* in_sizes, int n_in,
                              void* d_out, int out_size, void* d_ws, size_t ws_size,
                              hipStream_t stream) {
  const float* x  = (const float*)d_in[0];
  const int*   ei = (const int*)d_in[1];
  const float* ea = (const float*)d_in[2];
  const int* src = ei;
  const int* dst = ei + NE;

  auto P = [&](int c, int j) -> const float* {
    return (const float*)d_in[3 + c * 6 + j];
  };

  // workspace layout (round-10)
  float* h1  = (float*)d_ws;                          // NN*HID f32
  float* h2  = h1 + (size_t)NN * HID;                 // NN*HID f32
  _Float16* msg = (_Float16*)(h2 + (size_t)NN * HID); // NE*32 fp16
  int* cnt    = (int*)(msg + (size_t)NE * 32);        // NN
  int* rowptr = cnt + NN;                             // NN+1 (pad 50004)
  int* wptr   = rowptr + 50004;                       // NN+1 (pad)
  int* epos   = wptr + 50004;                         // NE
  int* bsum   = epos + NE;                            // NSB (pad 256)
  _Float16* w2h_c1 = (_Float16*)(bsum + 256);           // HSTR*32*16
  _Float16* w2h_c2 = w2h_c1 + (size_t)HSTR * 32 * 16;   // HSTR*32*32
  _Float16* w2h_mu = w2h_c2 + (size_t)HSTR * 32 * 32;   // HSTR*16*32
  _Float16* w2h_lv = w2h_mu + (size_t)HSTR * 16 * 32;
  float* w1t_c1 = (float*)(w2h_lv + (size_t)HSTR * 16 * 32);  // HE*EF each
  float* w1t_c2 = w1t_c1 + HE * EF;
  float* w1t_mu = w1t_c2 + HE * EF;
  float* w1t_lv = w1t_mu + HE * EF;

  _Float16* msgA = msg;                    // dual: NE*16
  _Float16* msgB = msg + (size_t)NE * 16;

  float* out_mu = (float*)d_out;
  float* out_lv = out_mu + (size_t)NN * LAT;

  // ---- CSR build ----
  hipMemsetAsync(cnt, 0, (size_t)NN * sizeof(int), stream);
  count_kernel<<<dim3((NE + 255) / 256), dim3(256), 0, stream>>>(dst, cnt);
  scan1<<<dim3(NSB), dim3(SCB), 0, stream>>>(cnt, bsum);
  scan2<<<dim3(1), dim3(SCB), 0, stream>>>(bsum);
  scan3<<<dim3(NSB), dim3(SCB), 0, stream>>>(cnt, bsum, rowptr, wptr);
  fill_kernel<<<dim3((NE + 255) / 256), dim3(256), 0, stream>>>(dst, wptr, epos);

  // ---- weight prep (w2 swizzle + w1 transpose) ----
  {
    int t1 = HSTR * 16 * 32, t2 = HSTR * 32 * 32, t3 = HSTR * 32 * 16;
    swizzle_kernel<<<dim3((t1 + 255) / 256), dim3(256), 0, stream>>>(
        P(0, 2), P(0, 3), P(0, 0), w2h_c1, w1t_c1, IN, HID);
    swizzle_kernel<<<dim3((t2 + 255) / 256), dim3(256), 0, stream>>>(
        P(1, 2), P(1, 3), P(1, 0), w2h_c2, w1t_c2, HID, HID);
    swizzle_kernel<<<dim3((t3 + 255) / 256), dim3(256), 0, stream>>>(
        P(2, 2), P(2, 3), P(2, 0), w2h_mu, w1t_mu, HID, LAT);
    swizzle_kernel<<<dim3((t3 + 255) / 256), dim3(256), 0, stream>>>(
        P(3, 2), P(3, 3), P(3, 0), w2h_lv, w1t_lv, HID, LAT);
  }

  const dim3 egrid((NTILE + 7) / 8), eblk(128);   // 128 edges / block, 2 waves

  // conv1: 16 -> 32, mean, relu
  nnconv_mfma<IN, HID, false><<<egrid, eblk, 0, stream>>>(
      x, src, ea, w1t_c1, P(0, 1), nullptr, nullptr, w2h_c1, nullptr,
      epos, msg, nullptr);
  finish_kernel<IN, HID, true, true>
      <<<dim3((NN * (HID / 4) + 255) / 256), dim3(256), 0, stream>>>(
          msg, rowptr, x, P(0, 4), P(0, 5), h1);

  // conv2: 32 -> 32, mean, relu
  nnconv_mfma<HID, HID, false><<<egrid, eblk, 0, stream>>>(
      h1, src, ea, w1t_c2, P(1, 1), nullptr, nullptr, w2h_c2, nullptr,
      epos, msg, nullptr);
  finish_kernel<HID, HID, true, true>
      <<<dim3((NN * (HID / 4) + 255) / 256), dim3(256), 0, stream>>>(
          msg, rowptr, h1, P(1, 4), P(1, 5), h2);

  // cmu + clv fused (own edge-MLPs; both streams in one K-pass)
  nnconv_mfma<HID, LAT, true><<<egrid, eblk, 0, stream>>>(
      h2, src, ea, w1t_mu, P(2, 1), w1t_lv, P(3, 1), w2h_mu, w2h_lv,
      epos, msgA, msgB);
  finish_dual<HID>
      <<<dim3((NN * (LAT / 4) + 255) / 256), dim3(256), 0, stream>>>(
          msgA, msgB, rowptr, h2, P(2, 4), P(2, 5), P(3, 4), P(3, 5),
          out_mu, out_lv);
}